// Round 3
// baseline (147.681 us; speedup 1.0000x reference)
//
#include <hip/hip_runtime.h>
#include <math.h>

#define NN 2048
#define EE 1024

typedef unsigned long long ull;

__device__ __forceinline__ float wave_reduce_sum(float v) {
  #pragma unroll
  for (int o = 32; o > 0; o >>= 1) v += __shfl_xor(v, o, 64);
  return v;
}

// dn[n] = deg>0 ? deg^-1/2 : 0, cnt[n] = nnz of row (H binary -> deg == nnz).
__global__ void k_dn(const float* __restrict__ H, float* __restrict__ dn,
                     int* __restrict__ cnt) {
  int wid = (blockIdx.x * blockDim.x + threadIdx.x) >> 6;
  int lane = threadIdx.x & 63;
  const float* row = H + (size_t)wid * EE;
  float s = 0.f;
  #pragma unroll
  for (int i = 0; i < EE; i += 64) s += row[i + lane];
  s = wave_reduce_sum(s);
  if (lane == 0) {
    dn[wid] = s > 0.f ? rsqrtf(s) : 0.f;
    cnt[wid] = (int)(s + 0.5f);
  }
}

// column-sum partials of H: dpart[by][e] = sum over 256 rows
__global__ void k_colsum_part(const float* __restrict__ H, float* __restrict__ dpart) {
  int e = blockIdx.x * 256 + threadIdx.x;
  int r0 = blockIdx.y * 256;
  float s = 0.f;
  #pragma unroll 8
  for (int n = 0; n < 256; ++n) s += H[(size_t)(r0 + n) * EE + e];
  dpart[blockIdx.y * EE + e] = s;
}

__global__ void k_de_fin(const float* __restrict__ dpart, float* __restrict__ de) {
  int e = blockIdx.x * 256 + threadIdx.x;
  float s = 0.f;
  #pragma unroll
  for (int p = 0; p < 8; ++p) s += dpart[p * EE + e];
  de[e] = s > 0.f ? 1.f / s : 0.f;
}

// single-block exclusive scan of cnt[2048] -> roff[2049]
__global__ void k_scan(const int* __restrict__ cnt, int* __restrict__ roff) {
  __shared__ int sc[256];
  int t = threadIdx.x;
  int base = t * 8;
  int v[8];
  int s = 0;
  #pragma unroll
  for (int j = 0; j < 8; ++j) { v[j] = cnt[base + j]; s += v[j]; }
  sc[t] = s;
  __syncthreads();
  for (int off = 1; off < 256; off <<= 1) {
    int a = (t >= off) ? sc[t - off] : 0;
    __syncthreads();
    sc[t] += a;
    __syncthreads();
  }
  int run = sc[t] - s;  // exclusive
  #pragma unroll
  for (int j = 0; j < 8; ++j) { roff[base + j] = run; run += v[j]; }
  if (t == 255) roff[2048] = run;
}

// per-row edge index list (ascending e order -> deterministic)
__global__ void k_fill(const float* __restrict__ H, const int* __restrict__ roff,
                       unsigned short* __restrict__ elist) {
  int n = (blockIdx.x * blockDim.x + threadIdx.x) >> 6;
  int lane = threadIdx.x & 63;
  const float* row = H + (size_t)n * EE;
  int base = roff[n];
  for (int i = 0; i < EE; i += 64) {
    float hv = row[i + lane];
    ull m = __ballot(hv != 0.f);
    int pos = base + __popcll(m & ((1ull << lane) - 1ull));
    if (hv != 0.f) elist[pos] = (unsigned short)(i + lane);
    base += __popcll(m);
  }
}

// sparse scores into zeroed Mmat: wave per row n; lane covers h=lane, h=lane+64
__global__ void k_sscore(const float* __restrict__ npb, const float* __restrict__ epb,
                         const float* __restrict__ W2, const float* __restrict__ b2,
                         const int* __restrict__ roff,
                         const unsigned short* __restrict__ elist,
                         float* __restrict__ Mmat) {
  int n = (blockIdx.x * blockDim.x + threadIdx.x) >> 6;
  int lane = threadIdx.x & 63;
  float npa = npb[(size_t)n * 128 + lane];
  float npc = npb[(size_t)n * 128 + 64 + lane];
  float w2a = W2[lane], w2b = W2[64 + lane];
  float b2v = b2[0];
  int s0 = roff[n], s1 = roff[n + 1];
  for (int s = s0; s < s1; ++s) {
    int e = elist[s];
    float tv = fmaxf(npa + epb[(size_t)e * 128 + lane], 0.f) * w2a
             + fmaxf(npc + epb[(size_t)e * 128 + 64 + lane], 0.f) * w2b;
    tv = wave_reduce_sum(tv);
    if (lane == 0)
      Mmat[(size_t)n * EE + e] = 1.f / (1.f + __expf(-(tv + b2v)));
  }
}

// out[r][h] = (addb ? b1[h] : 0) + sum_d in[r][d] * W1[h][woff+d]
__global__ void k_lin(const float* __restrict__ in, const float* __restrict__ W1,
                      const float* __restrict__ b1, float* __restrict__ out,
                      int woff, int addb) {
  __shared__ float Wl[128 * 65];
  __shared__ float xl[2][64];
  int t = threadIdx.x;
  for (int j = t; j < 128 * 64; j += 256) {
    int h = j >> 6, d = j & 63;
    Wl[h * 65 + d] = W1[h * 128 + woff + d];
  }
  int r0 = blockIdx.x * 2;
  if (t < 128) xl[t >> 6][t & 63] = in[(size_t)(r0 + (t >> 6)) * 64 + (t & 63)];
  __syncthreads();
  int rl = t >> 7;
  int h = t & 127;
  float acc = addb ? b1[h] : 0.f;
  #pragma unroll
  for (int d = 0; d < 64; ++d)
    acc += xl[rl][d] * Wl[h * 65 + d];
  out[(size_t)(r0 + rl) * 128 + h] = acc;
}

// split-K tiled GEMM: part[kb][m][d] = sum_{k in tile kb} A'[m][k] * sB[k]*B[k][d]
template <bool TRANSA>
__global__ void k_gemm(const float* __restrict__ A, int lda,
                       const float* __restrict__ B, const float* __restrict__ sB,
                       float* __restrict__ part, int Mdim) {
  __shared__ float Al[64 * 68];  // Al[k][m]
  __shared__ float Bl[64 * 68];  // Bl[k][d]
  int t = threadIdx.x;
  int m0 = blockIdx.x * 64, k0 = blockIdx.y * 64;
  #pragma unroll
  for (int p = 0; p < 16; ++p) {
    int idx = t + p * 256;
    int i = idx >> 6, j = idx & 63;
    if (TRANSA) Al[i * 68 + j] = A[(size_t)(k0 + i) * lda + m0 + j];
    else        Al[j * 68 + i] = A[(size_t)(m0 + i) * lda + k0 + j];
  }
  #pragma unroll
  for (int p = 0; p < 16; ++p) {
    int idx = t + p * 256;
    int i = idx >> 6, d = idx & 63;
    float v = B[(size_t)(k0 + i) * 64 + d];
    if (sB) v *= sB[k0 + i];
    Bl[i * 68 + d] = v;
  }
  __syncthreads();
  int me0 = (t & 15) * 4, d0 = (t >> 4) * 4;
  float acc[4][4] = {};
  #pragma unroll 8
  for (int k = 0; k < 64; ++k) {
    float av[4], bv[4];
    *(float4*)av = *(const float4*)&Al[k * 68 + me0];
    *(float4*)bv = *(const float4*)&Bl[k * 68 + d0];
    #pragma unroll
    for (int r = 0; r < 4; ++r)
      #pragma unroll
      for (int c = 0; c < 4; ++c)
        acc[r][c] += av[r] * bv[c];
  }
  float* po = part + (size_t)blockIdx.y * Mdim * 64;
  #pragma unroll
  for (int r = 0; r < 4; ++r)
    *(float4*)&po[(size_t)(m0 + me0 + r) * 64 + d0] = *(float4*)acc[r];
}

// out[m][d] = (smode ? scale[m] : 1) * sum_s part[s][m][d]
__global__ void k_red(const float* __restrict__ part, int S, int Mdim,
                      const float* __restrict__ scale, int smode,
                      float* __restrict__ out) {
  int idx = blockIdx.x * 256 + threadIdx.x;
  float s = 0.f;
  for (int p = 0; p < S; ++p) s += part[(size_t)p * Mdim * 64 + idx];
  if (smode) s *= scale[idx >> 6];
  out[idx] = s;
}

// fused: y[n][d] = dn[n] * sum_{p<16} part[p][n][d];  out = y @ Wl^T + bl
__global__ void k_out(const float* __restrict__ part, const float* __restrict__ dnv,
                      const float* __restrict__ Wlg, const float* __restrict__ bl,
                      float* __restrict__ out) {
  __shared__ float yl[4][64];
  __shared__ float Wlds[64][65];
  int t = threadIdx.x;
  int n0 = blockIdx.x * 4;
  for (int j = t; j < 4096; j += 256) Wlds[j >> 6][j & 63] = Wlg[j];
  {
    int nl = t >> 6, d = t & 63;
    int n = n0 + nl;
    float s = 0.f;
    #pragma unroll
    for (int p = 0; p < 16; ++p) s += part[(size_t)p * NN * 64 + (size_t)n * 64 + d];
    yl[nl][d] = dnv[n] * s;
  }
  __syncthreads();
  int rl = t >> 6, o = t & 63;
  float acc = bl[o];
  #pragma unroll
  for (int d = 0; d < 64; ++d)
    acc += yl[rl][d] * Wlds[o][d];
  out[(size_t)(n0 + rl) * 64 + o] = acc;
}

extern "C" void kernel_launch(void* const* d_in, const int* in_sizes, int n_in,
                              void* d_out, int out_size, void* d_ws, size_t ws_size,
                              hipStream_t stream) {
  const float* x  = (const float*)d_in[0];
  const float* H  = (const float*)d_in[1];
  const float* W1 = (const float*)d_in[2];
  const float* b1 = (const float*)d_in[3];
  const float* W2 = (const float*)d_in[4];
  const float* b2 = (const float*)d_in[5];
  const float* Wl = (const float*)d_in[6];
  const float* bl = (const float*)d_in[7];
  float* out = (float*)d_out;

  char* wsb = (char*)d_ws;
  float* dn    = (float*)wsb;            wsb += NN * 4;
  float* de    = (float*)wsb;            wsb += EE * 4;
  float* dpart = (float*)wsb;            wsb += 8 * EE * 4;
  int*   cnt   = (int*)wsb;              wsb += NN * 4;
  int*   roff  = (int*)wsb;              wsb += (NN + 4) * 4;
  unsigned short* elist = (unsigned short*)wsb; wsb += 512 * 1024 * 2;  // cap 512K nnz (actual ~105K)
  float* npb   = (float*)wsb;            wsb += NN * 128 * 4;
  float* epb   = (float*)wsb;            wsb += EE * 128 * 4;
  float* ef    = (float*)wsb;            wsb += EE * 64 * 4;
  float* w     = (float*)wsb;            wsb += EE * 64 * 4;
  float* Mmat  = (float*)wsb;            wsb += (size_t)NN * EE * 4;
  float* part  = (float*)wsb;            wsb += (size_t)NN * EE * 4;

  // zero the sparse score matrix (only nnz positions get written)
  hipMemsetAsync(Mmat, 0, (size_t)NN * EE * 4, stream);

  // degrees / scalings / sparsity structure
  hipLaunchKernelGGL(k_dn, dim3(NN / 4), dim3(256), 0, stream, H, dn, cnt);
  hipLaunchKernelGGL(k_colsum_part, dim3(EE / 256, 8), dim3(256), 0, stream, H, dpart);
  hipLaunchKernelGGL(k_de_fin, dim3(EE / 256), dim3(256), 0, stream, dpart, de);
  hipLaunchKernelGGL(k_scan, dim3(1), dim3(256), 0, stream, cnt, roff);
  hipLaunchKernelGGL(k_fill, dim3(NN / 4), dim3(256), 0, stream, H, roff, elist);
  // node projection
  hipLaunchKernelGGL(k_lin, dim3(NN / 2), dim3(256), 0, stream, x, W1, b1, npb, 0, 1);
  // ef = H^T @ x
  hipLaunchKernelGGL(k_gemm<true>, dim3(EE / 64, NN / 64), dim3(256), 0, stream,
                     H, EE, x, (const float*)nullptr, part, EE);
  hipLaunchKernelGGL(k_red, dim3(EE * 64 / 256), dim3(256), 0, stream,
                     part, NN / 64, EE, (const float*)nullptr, 0, ef);
  // edge projection
  hipLaunchKernelGGL(k_lin, dim3(EE / 2), dim3(256), 0, stream, ef, W1, b1, epb, 64, 0);
  // sparse masked attention scores
  hipLaunchKernelGGL(k_sscore, dim3(NN / 4), dim3(256), 0, stream,
                     npb, epb, W2, b2, roff, elist, Mmat);
  // t = M^T @ (dn*x);  w = de * t
  hipLaunchKernelGGL(k_gemm<true>, dim3(EE / 64, NN / 64), dim3(256), 0, stream,
                     Mmat, EE, x, dn, part, EE);
  hipLaunchKernelGGL(k_red, dim3(EE * 64 / 256), dim3(256), 0, stream,
                     part, NN / 64, EE, de, 1, w);
  // z = M @ w;  y = dn*z;  out = y @ Wl^T + bl  (reduction fused into k_out)
  hipLaunchKernelGGL(k_gemm<false>, dim3(NN / 64, EE / 64), dim3(256), 0, stream,
                     Mmat, EE, w, (const float*)nullptr, part, NN);
  hipLaunchKernelGGL(k_out, dim3(NN / 4), dim3(256), 0, stream, part, dn, Wl, bl, out);
}

// Round 4
// 116.238 us; speedup vs baseline: 1.2705x; 1.2705x over previous
//
#include <hip/hip_runtime.h>
#include <math.h>

#define NN 2048
#define EE 1024

typedef unsigned long long ull;

__device__ __forceinline__ float wave_reduce_sum(float v) {
  #pragma unroll
  for (int o = 32; o > 0; o >>= 1) v += __shfl_xor(v, o, 64);
  return v;
}

// dn[n] = deg>0 ? deg^-1/2 : 0, cnt[n] = nnz of row (H binary -> deg == nnz).
__global__ void k_dn(const float* __restrict__ H, float* __restrict__ dn,
                     int* __restrict__ cnt) {
  int wid = (blockIdx.x * blockDim.x + threadIdx.x) >> 6;
  int lane = threadIdx.x & 63;
  const float* row = H + (size_t)wid * EE;
  float s = 0.f;
  #pragma unroll
  for (int i = 0; i < EE; i += 64) s += row[i + lane];
  s = wave_reduce_sum(s);
  if (lane == 0) {
    dn[wid] = s > 0.f ? rsqrtf(s) : 0.f;
    cnt[wid] = (int)(s + 0.5f);
  }
}

// column-sum partials of H: dpart[by][e] = sum over 256 rows
__global__ void k_colsum_part(const float* __restrict__ H, float* __restrict__ dpart) {
  int e = blockIdx.x * 256 + threadIdx.x;
  int r0 = blockIdx.y * 256;
  float s = 0.f;
  #pragma unroll 8
  for (int n = 0; n < 256; ++n) s += H[(size_t)(r0 + n) * EE + e];
  dpart[blockIdx.y * EE + e] = s;
}

__global__ void k_de_fin(const float* __restrict__ dpart, float* __restrict__ de) {
  int e = blockIdx.x * 256 + threadIdx.x;
  float s = 0.f;
  #pragma unroll
  for (int p = 0; p < 8; ++p) s += dpart[p * EE + e];
  de[e] = s > 0.f ? 1.f / s : 0.f;
}

// single-block exclusive scan of cnt[2048] -> roff[2049]
__global__ void k_scan(const int* __restrict__ cnt, int* __restrict__ roff) {
  __shared__ int sc[256];
  int t = threadIdx.x;
  int base = t * 8;
  int v[8];
  int s = 0;
  #pragma unroll
  for (int j = 0; j < 8; ++j) { v[j] = cnt[base + j]; s += v[j]; }
  sc[t] = s;
  __syncthreads();
  for (int off = 1; off < 256; off <<= 1) {
    int a = (t >= off) ? sc[t - off] : 0;
    __syncthreads();
    sc[t] += a;
    __syncthreads();
  }
  int run = sc[t] - s;  // exclusive
  #pragma unroll
  for (int j = 0; j < 8; ++j) { roff[base + j] = run; run += v[j]; }
  if (t == 255) roff[2048] = run;
}

// flat nnz pair list, CSR order: plist[pos] = (n<<16)|e  (deterministic)
__global__ void k_fill(const float* __restrict__ H, const int* __restrict__ roff,
                       unsigned int* __restrict__ plist) {
  int n = (blockIdx.x * blockDim.x + threadIdx.x) >> 6;
  int lane = threadIdx.x & 63;
  const float* row = H + (size_t)n * EE;
  int base = roff[n];
  for (int i = 0; i < EE; i += 64) {
    float hv = row[i + lane];
    ull m = __ballot(hv != 0.f);
    int pos = base + __popcll(m & ((1ull << lane) - 1ull));
    if (hv != 0.f) plist[pos] = ((unsigned int)n << 16) | (unsigned int)(i + lane);
    base += __popcll(m);
  }
}

// pair-parallel scores: 4 lanes per nnz pair, each lane covers 32 of 128 h.
// Mmat (pre-zeroed) gets sigmoid(score) at nnz positions.
__global__ void k_pscore(const float* __restrict__ npb, const float* __restrict__ epb,
                         const float* __restrict__ W2, const float* __restrict__ b2,
                         const int* __restrict__ roff,
                         const unsigned int* __restrict__ plist,
                         float* __restrict__ Mmat) {
  int gid = blockIdx.x * blockDim.x + threadIdx.x;
  int sub = gid & 3;
  int slot = gid >> 2;
  int total = roff[NN];
  float4 w2r[8];
  #pragma unroll
  for (int j = 0; j < 8; ++j) w2r[j] = *(const float4*)&W2[j * 16 + sub * 4];
  float b2v = b2[0];
  int nslots = (gridDim.x * blockDim.x) >> 2;
  for (int p = slot; p < total; p += nslots) {
    unsigned int pk = plist[p];
    int n = pk >> 16, e = pk & 0xFFFF;
    const float* npr = npb + (size_t)n * 128;
    const float* epr = epb + (size_t)e * 128;
    float acc = 0.f;
    #pragma unroll
    for (int j = 0; j < 8; ++j) {
      float4 a = *(const float4*)&npr[j * 16 + sub * 4];
      float4 c = *(const float4*)&epr[j * 16 + sub * 4];
      acc += fmaxf(a.x + c.x, 0.f) * w2r[j].x + fmaxf(a.y + c.y, 0.f) * w2r[j].y
           + fmaxf(a.z + c.z, 0.f) * w2r[j].z + fmaxf(a.w + c.w, 0.f) * w2r[j].w;
    }
    acc += __shfl_xor(acc, 1, 64);
    acc += __shfl_xor(acc, 2, 64);
    if (sub == 0)
      Mmat[(size_t)n * EE + e] = 1.f / (1.f + __expf(-(acc + b2v)));
  }
}

// out[r][h] = (addb ? b1[h] : 0) + sum_d in[r][d] * W1[h][woff+d]
__global__ void k_lin(const float* __restrict__ in, const float* __restrict__ W1,
                      const float* __restrict__ b1, float* __restrict__ out,
                      int woff, int addb) {
  __shared__ float Wl[128 * 65];
  __shared__ float xl[2][64];
  int t = threadIdx.x;
  for (int j = t; j < 128 * 64; j += 256) {
    int h = j >> 6, d = j & 63;
    Wl[h * 65 + d] = W1[h * 128 + woff + d];
  }
  int r0 = blockIdx.x * 2;
  if (t < 128) xl[t >> 6][t & 63] = in[(size_t)(r0 + (t >> 6)) * 64 + (t & 63)];
  __syncthreads();
  int rl = t >> 7;
  int h = t & 127;
  float acc = addb ? b1[h] : 0.f;
  #pragma unroll
  for (int d = 0; d < 64; ++d)
    acc += xl[rl][d] * Wl[h * 65 + d];
  out[(size_t)(r0 + rl) * 128 + h] = acc;
}

// split-K tiled GEMM: part[kb][m][d] = sum_{k in tile kb} A'[m][k] * sB[k]*B[k][d]
template <bool TRANSA>
__global__ void k_gemm(const float* __restrict__ A, int lda,
                       const float* __restrict__ B, const float* __restrict__ sB,
                       float* __restrict__ part, int Mdim) {
  __shared__ float Al[64 * 68];  // Al[k][m]
  __shared__ float Bl[64 * 68];  // Bl[k][d]
  int t = threadIdx.x;
  int m0 = blockIdx.x * 64, k0 = blockIdx.y * 64;
  #pragma unroll
  for (int p = 0; p < 16; ++p) {
    int idx = t + p * 256;
    int i = idx >> 6, j = idx & 63;
    if (TRANSA) Al[i * 68 + j] = A[(size_t)(k0 + i) * lda + m0 + j];
    else        Al[j * 68 + i] = A[(size_t)(m0 + i) * lda + k0 + j];
  }
  #pragma unroll
  for (int p = 0; p < 16; ++p) {
    int idx = t + p * 256;
    int i = idx >> 6, d = idx & 63;
    float v = B[(size_t)(k0 + i) * 64 + d];
    if (sB) v *= sB[k0 + i];
    Bl[i * 68 + d] = v;
  }
  __syncthreads();
  int me0 = (t & 15) * 4, d0 = (t >> 4) * 4;
  float acc[4][4] = {};
  #pragma unroll 8
  for (int k = 0; k < 64; ++k) {
    float av[4], bv[4];
    *(float4*)av = *(const float4*)&Al[k * 68 + me0];
    *(float4*)bv = *(const float4*)&Bl[k * 68 + d0];
    #pragma unroll
    for (int r = 0; r < 4; ++r)
      #pragma unroll
      for (int c = 0; c < 4; ++c)
        acc[r][c] += av[r] * bv[c];
  }
  float* po = part + (size_t)blockIdx.y * Mdim * 64;
  #pragma unroll
  for (int r = 0; r < 4; ++r)
    *(float4*)&po[(size_t)(m0 + me0 + r) * 64 + d0] = *(float4*)acc[r];
}

// out[m][d] = (smode ? scale[m] : 1) * sum_s part[s][m][d]
__global__ void k_red(const float* __restrict__ part, int S, int Mdim,
                      const float* __restrict__ scale, int smode,
                      float* __restrict__ out) {
  int idx = blockIdx.x * 256 + threadIdx.x;
  float s = 0.f;
  for (int p = 0; p < S; ++p) s += part[(size_t)p * Mdim * 64 + idx];
  if (smode) s *= scale[idx >> 6];
  out[idx] = s;
}

// fused: y[n][d] = dn[n] * sum_{p<16} part[p][n][d];  out = y @ Wl^T + bl
__global__ void k_out(const float* __restrict__ part, const float* __restrict__ dnv,
                      const float* __restrict__ Wlg, const float* __restrict__ bl,
                      float* __restrict__ out) {
  __shared__ float yl[4][64];
  __shared__ float Wlds[64][65];
  int t = threadIdx.x;
  int n0 = blockIdx.x * 4;
  for (int j = t; j < 4096; j += 256) Wlds[j >> 6][j & 63] = Wlg[j];
  {
    int nl = t >> 6, d = t & 63;
    int n = n0 + nl;
    float s = 0.f;
    #pragma unroll
    for (int p = 0; p < 16; ++p) s += part[(size_t)p * NN * 64 + (size_t)n * 64 + d];
    yl[nl][d] = dnv[n] * s;
  }
  __syncthreads();
  int rl = t >> 6, o = t & 63;
  float acc = bl[o];
  #pragma unroll
  for (int d = 0; d < 64; ++d)
    acc += yl[rl][d] * Wlds[o][d];
  out[(size_t)(n0 + rl) * 64 + o] = acc;
}

extern "C" void kernel_launch(void* const* d_in, const int* in_sizes, int n_in,
                              void* d_out, int out_size, void* d_ws, size_t ws_size,
                              hipStream_t stream) {
  const float* x  = (const float*)d_in[0];
  const float* H  = (const float*)d_in[1];
  const float* W1 = (const float*)d_in[2];
  const float* b1 = (const float*)d_in[3];
  const float* W2 = (const float*)d_in[4];
  const float* b2 = (const float*)d_in[5];
  const float* Wl = (const float*)d_in[6];
  const float* bl = (const float*)d_in[7];
  float* out = (float*)d_out;

  char* wsb = (char*)d_ws;
  float* dn    = (float*)wsb;            wsb += NN * 4;
  float* de    = (float*)wsb;            wsb += EE * 4;
  float* dpart = (float*)wsb;            wsb += 8 * EE * 4;
  int*   cnt   = (int*)wsb;              wsb += NN * 4;
  int*   roff  = (int*)wsb;              wsb += (NN + 4) * 4;
  unsigned int* plist = (unsigned int*)wsb; wsb += 512 * 1024 * 4;  // cap 512K nnz (actual ~105K)
  float* npb   = (float*)wsb;            wsb += NN * 128 * 4;
  float* epb   = (float*)wsb;            wsb += EE * 128 * 4;
  float* ef    = (float*)wsb;            wsb += EE * 64 * 4;
  float* w     = (float*)wsb;            wsb += EE * 64 * 4;
  float* Mmat  = (float*)wsb;            wsb += (size_t)NN * EE * 4;
  float* part  = (float*)wsb;            wsb += (size_t)NN * EE * 4;

  // zero the sparse score matrix (only nnz positions get written)
  hipMemsetAsync(Mmat, 0, (size_t)NN * EE * 4, stream);

  // degrees / scalings / sparsity structure
  hipLaunchKernelGGL(k_dn, dim3(NN / 4), dim3(256), 0, stream, H, dn, cnt);
  hipLaunchKernelGGL(k_colsum_part, dim3(EE / 256, 8), dim3(256), 0, stream, H, dpart);
  hipLaunchKernelGGL(k_de_fin, dim3(EE / 256), dim3(256), 0, stream, dpart, de);
  hipLaunchKernelGGL(k_scan, dim3(1), dim3(256), 0, stream, cnt, roff);
  hipLaunchKernelGGL(k_fill, dim3(NN / 4), dim3(256), 0, stream, H, roff, plist);
  // node projection
  hipLaunchKernelGGL(k_lin, dim3(NN / 2), dim3(256), 0, stream, x, W1, b1, npb, 0, 1);
  // ef = H^T @ x
  hipLaunchKernelGGL(k_gemm<true>, dim3(EE / 64, NN / 64), dim3(256), 0, stream,
                     H, EE, x, (const float*)nullptr, part, EE);
  hipLaunchKernelGGL(k_red, dim3(EE * 64 / 256), dim3(256), 0, stream,
                     part, NN / 64, EE, (const float*)nullptr, 0, ef);
  // edge projection
  hipLaunchKernelGGL(k_lin, dim3(EE / 2), dim3(256), 0, stream, ef, W1, b1, epb, 64, 0);
  // pair-parallel masked attention scores
  hipLaunchKernelGGL(k_pscore, dim3(2048), dim3(256), 0, stream,
                     npb, epb, W2, b2, roff, plist, Mmat);
  // t = M^T @ (dn*x);  w = de * t
  hipLaunchKernelGGL(k_gemm<true>, dim3(EE / 64, NN / 64), dim3(256), 0, stream,
                     Mmat, EE, x, dn, part, EE);
  hipLaunchKernelGGL(k_red, dim3(EE * 64 / 256), dim3(256), 0, stream,
                     part, NN / 64, EE, de, 1, w);
  // z = M @ w;  y = dn*z;  out = y @ Wl^T + bl  (reduction fused into k_out)
  hipLaunchKernelGGL(k_gemm<false>, dim3(NN / 64, EE / 64), dim3(256), 0, stream,
                     Mmat, EE, w, (const float*)nullptr, part, NN);
  hipLaunchKernelGGL(k_out, dim3(NN / 4), dim3(256), 0, stream, part, dn, Wl, bl, out);
}